// Round 1
// 983.469 us; speedup vs baseline: 1.1277x; 1.1277x over previous
//
#include <hip/hip_runtime.h>
#include <stdint.h>

// ---------- types ----------
typedef __bf16 bf16x8 __attribute__((ext_vector_type(8)));
typedef float  f32x4  __attribute__((ext_vector_type(4)));

#define AS1 __attribute__((address_space(1)))
#define AS3 __attribute__((address_space(3)))

// async global->LDS, 16B per lane; LDS dest = wave-uniform base + lane*16
__device__ __forceinline__ void gload_lds16(const void* g, void* l) {
    __builtin_amdgcn_global_load_lds((const AS1 uint32_t*)g, (AS3 uint32_t*)l, 16, 0, 0);
}

// Problem constants: B=32, c_in=64, N=512, L=64, K=3, c_out=64
// j index = k*512 + n  (contraction dim, 1536)
// f2 index = o*64 + l  (output "column" dim, 4096)

// ---------- T2 = 2*adj@adj - I  (fp32, 1 MiB in ws) ----------
__global__ __launch_bounds__(256) void k_t2(const float* __restrict__ adj,
                                            float* __restrict__ T2f) {
    const int q = blockIdx.x, tx = threadIdx.x;
    float a0 = 0.f, a1 = 0.f;
    for (int m = 0; m < 512; ++m) {
        const float av = adj[q*512 + m];           // wave-uniform -> scalar load
        a0 += av * adj[m*512 + tx];
        a1 += av * adj[m*512 + tx + 256];
    }
    T2f[q*512 + tx      ] = 2.f*a0 - ((q == tx      ) ? 1.f : 0.f);
    T2f[q*512 + tx + 256] = 2.f*a1 - ((q == tx + 256) ? 1.f : 0.f);
}

// ---------- W2[f=k*64+o][c] = bf16(W[o][c*3+k]) ----------
__global__ __launch_bounds__(256) void k_w2(const float* __restrict__ W,
                                            __bf16* __restrict__ W2bf) {
    const int t = blockIdx.x*256 + threadIdx.x;    // 48*256 = 12288 = 192*64
    const int f = t >> 6, c = t & 63;
    const int k = f >> 6, o = f & 63;
    W2bf[t] = (__bf16)W[o*192 + c*3 + k];
}

// ---------- A-build: Abf[bb][q][j] = bf16(ds[b,q,n] * T_k[q,n]) ----------
__global__ __launch_bounds__(256) void k_abuild(const float* __restrict__ ds,
                                                const float* __restrict__ adj,
                                                const float* __restrict__ T2f,
                                                __bf16* __restrict__ Abf, int b0) {
    const int bx = blockIdx.x;
    const int bb = bx >> 9, q = bx & 511;
    const int b  = b0 + bb;
    const float* dsr  = ds  + ((size_t)b*512 + q)*512;
    __bf16*      arow = Abf + ((size_t)bb*512 + q)*1536;
    for (int j = threadIdx.x; j < 1536; j += 256) {
        const int k = j >> 9, n = j & 511;
        float tv;
        if      (k == 0) tv = (q == n) ? 1.0f : 0.0f;
        else if (k == 1) tv = adj[q*512 + n];
        else             tv = T2f[q*512 + n];
        arow[j] = (__bf16)(dsr[n] * tv);
    }
}

// ---------- Stage 1: zT[bb][(o,l)][(k,n)] = bf16( sum_c W2[f][c]*x[b,c,n,l] ) ----------
// Block = (bb, ng, lg): n-range 32, l-range 4. MFMA [192 x 64] @ [64 x 128].
// LDS: W2s[192][72] (27648B) + Xs[128][72] (18432B); epilogue reuses as Ds[192][136] (52224B).
// XCD-chunk swizzle: hw blockIdx round-robins over the 8 XCDs (private L2s).
// Remap so each XCD owns a CONTIGUOUS logical chunk -> the 16 lg-blocks that
// share one (bb,ng) x-slice (and each 64B x-cacheline, shared by 4 lg) are
// co-resident on the SAME XCD L2. Kills the 4x x-read over-fetch.
__global__ __launch_bounds__(256) void k_zprep(const float* __restrict__ x,
                                               const __bf16* __restrict__ W2bf,
                                               __bf16* __restrict__ zT, int b0) {
    __shared__ __align__(16) char lds_raw[52224];
    __bf16* W2s = (__bf16*)lds_raw;              // [192][72] padded (rows 144B, 16B-aligned)
    __bf16* Xs  = (__bf16*)(lds_raw + 27648);    // [128][72] padded, layout [m'][c]
    __bf16* Dsh = (__bf16*)lds_raw;              // [192][136] (reused after barrier)

    const int t = threadIdx.x, lane = t & 63, w = t >> 6;
    const int nb = gridDim.x;                    // bc*256, always %8 == 0
    int bx = blockIdx.x;
    bx = (bx & 7) * (nb >> 3) + (bx >> 3);       // bijective xcd-chunk swizzle
    const int bb = bx >> 8;  const int r = bx & 255;
    const int ng = r >> 4, lg = r & 15;          // lg fastest: 16 lg-blocks logical-adjacent
    const int l0 = lg*4, n0 = ng*32;
    const int b  = b0 + bb;

    // W2 -> LDS (padded rows)
    #pragma unroll
    for (int i = 0; i < 6; ++i) {
        const int u = t + 256*i, f = u >> 3, seg = u & 7;
        *(bf16x8*)(W2s + f*72 + seg*8) = *(const bf16x8*)(W2bf + f*64 + seg*8);
    }
    // x -> LDS, fp32->bf16, transpose to [m' = lp*32+nn][c]
    #pragma unroll
    for (int p = 0; p < 8; ++p) {
        const int u = t + 256*p, c = u >> 5, nn = u & 31;
        const float4 v = *(const float4*)(x + (((size_t)b*64 + c)*512 + (n0 + nn))*64 + l0);
        Xs[(nn     )*72 + c] = (__bf16)v.x;
        Xs[(nn + 32)*72 + c] = (__bf16)v.y;
        Xs[(nn + 64)*72 + c] = (__bf16)v.z;
        Xs[(nn + 96)*72 + c] = (__bf16)v.w;
    }
    __syncthreads();

    f32x4 acc[3][8] = {};
    const int fw = w*48, m15 = lane & 15, quad = lane >> 4;
    #pragma unroll
    for (int ks = 0; ks < 2; ++ks) {
        const int c0 = ks*32 + quad*8;
        bf16x8 a[3], bv[8];
        #pragma unroll
        for (int i = 0; i < 3; ++i)
            a[i] = *(const bf16x8*)(W2s + (fw + i*16 + m15)*72 + c0);
        #pragma unroll
        for (int j = 0; j < 8; ++j)
            bv[j] = *(const bf16x8*)(Xs + (j*16 + m15)*72 + c0);
        #pragma unroll
        for (int i = 0; i < 3; ++i)
            #pragma unroll
            for (int j = 0; j < 8; ++j)
                acc[i][j] = __builtin_amdgcn_mfma_f32_16x16x32_bf16(a[i], bv[j], acc[i][j], 0, 0, 0);
    }
    __syncthreads();

    // D (C-layout: row=quad*4+rr, col=m') -> Dsh[f][m'] as bf16
    #pragma unroll
    for (int i = 0; i < 3; ++i)
        #pragma unroll
        for (int j = 0; j < 8; ++j) {
            const int f = fw + i*16 + quad*4, m = j*16 + m15;
            #pragma unroll
            for (int rr = 0; rr < 4; ++rr)
                Dsh[(f + rr)*136 + m] = (__bf16)acc[i][j][rr];
        }
    __syncthreads();

    // transpose-store: for (f=(k,o), l') write 32-long n-run (64B contiguous, line-aligned)
    #pragma unroll
    for (int i = 0; i < 3; ++i) {
        const int u = t + 256*i, f = u >> 2, lp = u & 3;
        const int k = f >> 6, o = f & 63;
        __bf16* dst = zT + ((size_t)bb*4096 + o*64 + (l0 + lp))*1536 + k*512 + n0;
        const __bf16* srcp = Dsh + f*136 + lp*32;
        *(bf16x8*)(dst +  0) = *(const bf16x8*)(srcp +  0);
        *(bf16x8*)(dst +  8) = *(const bf16x8*)(srcp +  8);
        *(bf16x8*)(dst + 16) = *(const bf16x8*)(srcp + 16);
        *(bf16x8*)(dst + 24) = *(const bf16x8*)(srcp + 24);
    }
}

// ---------- Stage 2: out[b][o][q][l] = A_b[512x1536] @ zT_b^T + bias ----------
// m97-style: 128x128 tile, BK=32, 4 waves (2x2 of 64x64), global_load_lds width 16.
// Same XCD-chunk swizzle: the 4 qt-blocks sharing a 384KB B-panel (and the
// per-bb 1.5MiB A) land on one XCD's L2 instead of 4 different XCDs.
__global__ __launch_bounds__(256) void k_gemm(const __bf16* __restrict__ Abf,
                                              const __bf16* __restrict__ zT,
                                              const float* __restrict__ bias,
                                              float* __restrict__ out, int b0) {
    __shared__ __align__(16) __bf16 As[128*32];
    __shared__ __align__(16) __bf16 Bs[128*32];
    const int t = threadIdx.x, lane = t & 63, w = t >> 6;
    const int nb = gridDim.x;                    // bc*128, always %8 == 0
    int bx = blockIdx.x;
    bx = (bx & 7) * (nb >> 3) + (bx >> 3);       // bijective xcd-chunk swizzle
    const int bb = bx >> 7;  const int r = bx & 127;
    const int qt = r & 3, ft = r >> 2;          // qt fastest: 4 B-sharing blocks logical-adjacent
    const int q0 = qt*128, f20 = ft*128;
    const __bf16* Ab = Abf + (size_t)bb*512 *1536;
    const __bf16* Bb = zT  + (size_t)bb*4096*1536;
    const int lrow = lane >> 2, lseg = lane & 3;
    const int m15 = lane & 15, quad = lane >> 4;
    const int wq = (w >> 1)*64, wf = (w & 1)*64;

    f32x4 acc[4][4] = {};
    for (int j0 = 0; j0 < 1536; j0 += 32) {
        #pragma unroll
        for (int i = 0; i < 2; ++i) {
            const int rb = (w*2 + i)*16;        // 16 rows per wave-instr, LDS dest = base+lane*16
            gload_lds16(Ab + ((size_t)(q0  + rb + lrow))*1536 + j0 + lseg*8, As + rb*32);
            gload_lds16(Bb + ((size_t)(f20 + rb + lrow))*1536 + j0 + lseg*8, Bs + rb*32);
        }
        __syncthreads();
        bf16x8 av[4], bv[4];
        const int co = quad*8;
        #pragma unroll
        for (int i = 0; i < 4; ++i) av[i] = *(const bf16x8*)(As + (wq + i*16 + m15)*32 + co);
        #pragma unroll
        for (int j = 0; j < 4; ++j) bv[j] = *(const bf16x8*)(Bs + (wf + j*16 + m15)*32 + co);
        #pragma unroll
        for (int i = 0; i < 4; ++i)
            #pragma unroll
            for (int j = 0; j < 4; ++j)
                acc[i][j] = __builtin_amdgcn_mfma_f32_16x16x32_bf16(av[i], bv[j], acc[i][j], 0, 0, 0);
        __syncthreads();
    }

    const int b = b0 + bb;
    #pragma unroll
    for (int j = 0; j < 4; ++j) {
        const int f2 = f20 + wf + j*16 + m15;
        const int o = f2 >> 6, l = f2 & 63;
        const float bi = bias[o];
        #pragma unroll
        for (int i = 0; i < 4; ++i) {
            const int qb = q0 + wq + i*16 + quad*4;
            float* dst = out + (((size_t)b*64 + o)*512 + qb)*64 + l;
            dst[  0] = acc[i][j][0] + bi;       // q-stride in out is 64 floats
            dst[ 64] = acc[i][j][1] + bi;
            dst[128] = acc[i][j][2] + bi;
            dst[192] = acc[i][j][3] + bi;
        }
    }
}

// ---------- host ----------
extern "C" void kernel_launch(void* const* d_in, const int* in_sizes, int n_in,
                              void* d_out, int out_size, void* d_ws, size_t ws_size,
                              hipStream_t stream) {
    (void)in_sizes; (void)n_in; (void)out_size;
    const float* x    = (const float*)d_in[0];
    const float* adj  = (const float*)d_in[1];
    const float* ds   = (const float*)d_in[2];
    const float* W    = (const float*)d_in[3];
    const float* bias = (const float*)d_in[4];
    float* out = (float*)d_out;
    char*  ws  = (char*)d_ws;

    float*  T2f  = (float*)ws;                      // 512*512*4 = 1 MiB
    __bf16* W2bf = (__bf16*)(ws + (1u << 20));      // 24576 B
    char*   chunk0 = ws + (1u << 20) + 32768;

    const size_t abytes = (size_t)512 *1536*2;      // per-b Abf  (1.5 MiB)
    const size_t zbytes = (size_t)4096*1536*2;      // per-b zT   (12 MiB)
    const size_t perb   = abytes + zbytes;
    const size_t head   = (1u << 20) + 32768;

    int bpc = 1;                                    // batches per chunk, sized to ws
    if (ws_size > head) {
        size_t a = (ws_size - head) / perb;
        bpc = (a < 1) ? 1 : (a > 32 ? 32 : (int)a);
    }

    k_t2<<<dim3(512), dim3(256), 0, stream>>>(adj, T2f);
    k_w2<<<dim3(48),  dim3(256), 0, stream>>>(W, W2bf);

    __bf16* Abf = (__bf16*)chunk0;
    __bf16* zTp = (__bf16*)(chunk0 + (size_t)bpc*abytes);
    for (int b0 = 0; b0 < 32; b0 += bpc) {
        const int bc = (32 - b0 < bpc) ? (32 - b0) : bpc;
        k_abuild<<<dim3(bc*512), dim3(256), 0, stream>>>(ds, adj, T2f, Abf, b0);
        k_zprep <<<dim3(bc*256), dim3(256), 0, stream>>>(x, W2bf, zTp, b0);
        k_gemm  <<<dim3(bc*128), dim3(256), 0, stream>>>(Abf, zTp, bias, out, b0);
    }
}

// Round 2
// 944.681 us; speedup vs baseline: 1.1740x; 1.0411x over previous
//
#include <hip/hip_runtime.h>
#include <stdint.h>

// ---------- types ----------
typedef __bf16 bf16x8 __attribute__((ext_vector_type(8)));
typedef float  f32x4  __attribute__((ext_vector_type(4)));

#define AS1 __attribute__((address_space(1)))
#define AS3 __attribute__((address_space(3)))

// async global->LDS, 16B per lane; LDS dest = wave-uniform base + lane*16
__device__ __forceinline__ void gload_lds16(const void* g, void* l) {
    __builtin_amdgcn_global_load_lds((const AS1 uint32_t*)g, (AS3 uint32_t*)l, 16, 0, 0);
}

__device__ __forceinline__ float bf2f(unsigned short u) {
    union { unsigned int i; float f; } v; v.i = ((unsigned int)u) << 16; return v.f;
}

// Problem constants: B=32, c_in=64, N=512, L=64, K=3, c_out=64
// GEMM contraction j' = (k-1)*512 + n for k in {1,2}  (K' = 1024)
// k=0 block of A is diagonal: A[q][0*512+n] = delta(q,n)*ds[b,q,q]
//   -> folded into epilogue: acc += dsdiag[b][q] * z0[f2][q]
// f2 index = o*64 + l  (output "column" dim, 4096)

// ---------- T2 = 2*adj@adj - I  (fp32, 1 MiB in ws) ----------
__global__ __launch_bounds__(256) void k_t2(const float* __restrict__ adj,
                                            float* __restrict__ T2f) {
    const int q = blockIdx.x, tx = threadIdx.x;
    float a0 = 0.f, a1 = 0.f;
    for (int m = 0; m < 512; ++m) {
        const float av = adj[q*512 + m];           // wave-uniform -> scalar load
        a0 += av * adj[m*512 + tx];
        a1 += av * adj[m*512 + tx + 256];
    }
    T2f[q*512 + tx      ] = 2.f*a0 - ((q == tx      ) ? 1.f : 0.f);
    T2f[q*512 + tx + 256] = 2.f*a1 - ((q == tx + 256) ? 1.f : 0.f);
}

// ---------- W2[f=k*64+o][c] = bf16(W[o][c*3+k]) ----------
__global__ __launch_bounds__(256) void k_w2(const float* __restrict__ W,
                                            __bf16* __restrict__ W2bf) {
    const int t = blockIdx.x*256 + threadIdx.x;    // 48*256 = 12288 = 192*64
    const int f = t >> 6, c = t & 63;
    const int k = f >> 6, o = f & 63;
    W2bf[t] = (__bf16)W[o*192 + c*3 + k];
}

// ---------- A-build: Abf[bb][q][j'] = bf16(ds[b,q,n] * T_k[q,n]), k in {1,2} ----------
// Also emits dsd[bb][q] = ds[b,q,q] (fp32) for the k=0 diagonal epilogue term.
__global__ __launch_bounds__(256) void k_abuild(const float* __restrict__ ds,
                                                const float* __restrict__ adj,
                                                const float* __restrict__ T2f,
                                                __bf16* __restrict__ Abf,
                                                float* __restrict__ dsd, int b0) {
    const int bx = blockIdx.x;
    const int bb = bx >> 9, q = bx & 511;
    const int b  = b0 + bb;
    const float* dsr  = ds  + ((size_t)b*512 + q)*512;
    __bf16*      arow = Abf + ((size_t)bb*512 + q)*1024;
    if (threadIdx.x == 0) dsd[bb*512 + q] = dsr[q];
    for (int j = threadIdx.x; j < 1024; j += 256) {
        const int n = j & 511;
        const float tv = (j < 512) ? adj[q*512 + n] : T2f[q*512 + n];
        arow[j] = (__bf16)(dsr[n] * tv);
    }
}

// ---------- Stage 1: zT[bb][(o,l)][(k,n)] = bf16( sum_c W2[f][c]*x[b,c,n,l] ) ----------
// Block = (bb, ng, lg): n-range 32, l-range 4. MFMA [192 x 64] @ [64 x 128].
// LDS: W2s[192][72] (27648B) + Xs[128][72] (18432B); epilogue reuses as Ds[192][136] (52224B).
// XCD-chunk swizzle keeps the 16 lg-blocks of one (bb,ng) x-slice on one XCD L2.
__global__ __launch_bounds__(256) void k_zprep(const float* __restrict__ x,
                                               const __bf16* __restrict__ W2bf,
                                               __bf16* __restrict__ zT, int b0) {
    __shared__ __align__(16) char lds_raw[52224];
    __bf16* W2s = (__bf16*)lds_raw;              // [192][72] padded (rows 144B, 16B-aligned)
    __bf16* Xs  = (__bf16*)(lds_raw + 27648);    // [128][72] padded, layout [m'][c]
    __bf16* Dsh = (__bf16*)lds_raw;              // [192][136] (reused after barrier)

    const int t = threadIdx.x, lane = t & 63, w = t >> 6;
    const int nb = gridDim.x;                    // bc*256, always %8 == 0
    int bx = blockIdx.x;
    bx = (bx & 7) * (nb >> 3) + (bx >> 3);       // bijective xcd-chunk swizzle
    const int bb = bx >> 8;  const int r = bx & 255;
    const int ng = r >> 4, lg = r & 15;          // lg fastest: 16 lg-blocks logical-adjacent
    const int l0 = lg*4, n0 = ng*32;
    const int b  = b0 + bb;

    // W2 -> LDS (padded rows)
    #pragma unroll
    for (int i = 0; i < 6; ++i) {
        const int u = t + 256*i, f = u >> 3, seg = u & 7;
        *(bf16x8*)(W2s + f*72 + seg*8) = *(const bf16x8*)(W2bf + f*64 + seg*8);
    }
    // x -> LDS, fp32->bf16, transpose to [m' = lp*32+nn][c]
    #pragma unroll
    for (int p = 0; p < 8; ++p) {
        const int u = t + 256*p, c = u >> 5, nn = u & 31;
        const float4 v = *(const float4*)(x + (((size_t)b*64 + c)*512 + (n0 + nn))*64 + l0);
        Xs[(nn     )*72 + c] = (__bf16)v.x;
        Xs[(nn + 32)*72 + c] = (__bf16)v.y;
        Xs[(nn + 64)*72 + c] = (__bf16)v.z;
        Xs[(nn + 96)*72 + c] = (__bf16)v.w;
    }
    __syncthreads();

    f32x4 acc[3][8] = {};
    const int fw = w*48, m15 = lane & 15, quad = lane >> 4;
    #pragma unroll
    for (int ks = 0; ks < 2; ++ks) {
        const int c0 = ks*32 + quad*8;
        bf16x8 a[3], bv[8];
        #pragma unroll
        for (int i = 0; i < 3; ++i)
            a[i] = *(const bf16x8*)(W2s + (fw + i*16 + m15)*72 + c0);
        #pragma unroll
        for (int j = 0; j < 8; ++j)
            bv[j] = *(const bf16x8*)(Xs + (j*16 + m15)*72 + c0);
        #pragma unroll
        for (int i = 0; i < 3; ++i)
            #pragma unroll
            for (int j = 0; j < 8; ++j)
                acc[i][j] = __builtin_amdgcn_mfma_f32_16x16x32_bf16(a[i], bv[j], acc[i][j], 0, 0, 0);
    }
    __syncthreads();

    // D (C-layout: row=quad*4+rr, col=m') -> Dsh[f][m'] as bf16
    #pragma unroll
    for (int i = 0; i < 3; ++i)
        #pragma unroll
        for (int j = 0; j < 8; ++j) {
            const int f = fw + i*16 + quad*4, m = j*16 + m15;
            #pragma unroll
            for (int rr = 0; rr < 4; ++rr)
                Dsh[(f + rr)*136 + m] = (__bf16)acc[i][j][rr];
        }
    __syncthreads();

    // transpose-store: for (f=(k,o), l') write 32-long n-run (64B contiguous, line-aligned)
    #pragma unroll
    for (int i = 0; i < 3; ++i) {
        const int u = t + 256*i, f = u >> 2, lp = u & 3;
        const int k = f >> 6, o = f & 63;
        __bf16* dst = zT + ((size_t)bb*4096 + o*64 + (l0 + lp))*1536 + k*512 + n0;
        const __bf16* srcp = Dsh + f*136 + lp*32;
        *(bf16x8*)(dst +  0) = *(const bf16x8*)(srcp +  0);
        *(bf16x8*)(dst +  8) = *(const bf16x8*)(srcp +  8);
        *(bf16x8*)(dst + 16) = *(const bf16x8*)(srcp + 16);
        *(bf16x8*)(dst + 24) = *(const bf16x8*)(srcp + 24);
    }
}

// ---------- Stage 2: out[b][o][q][l] = A_b[512x1024] @ zT_b(k=1,2)^T + ds_diag*z0 + bias ----------
// 128x128 tile, BK=32, 4 waves (2x2 of 64x64), global_load_lds width 16.
// T3-minimum double-buffer: STAGE(buf^1, t+1) issued BEFORE ds_read+MFMA of buf[cur];
// single __syncthreads() (vmcnt(0)+lgkmcnt(0)+barrier) per K-step.
// Safety: barrier at end of iter t-1 ensures (a) every wave finished its ds_reads of
// buf^1 (lgkm drained pre-MFMA) before iter t overwrites it, (b) buf[cur] fully landed.
__global__ __launch_bounds__(256) void k_gemm(const __bf16* __restrict__ Abf,
                                              const __bf16* __restrict__ zT,
                                              const float* __restrict__ dsd,
                                              const float* __restrict__ bias,
                                              float* __restrict__ out, int b0) {
    __shared__ __align__(16) __bf16 As[2][128*32];
    __shared__ __align__(16) __bf16 Bs[2][128*32];
    const int t = threadIdx.x, lane = t & 63, w = t >> 6;
    const int nb = gridDim.x;                    // bc*128, always %8 == 0
    int bx = blockIdx.x;
    bx = (bx & 7) * (nb >> 3) + (bx >> 3);       // bijective xcd-chunk swizzle
    const int bb = bx >> 7;  const int r = bx & 127;
    const int qt = r & 3, ft = r >> 2;           // qt fastest: 4 B-sharing blocks logical-adjacent
    const int q0 = qt*128, f20 = ft*128;
    const __bf16* Ab = Abf + (size_t)bb*512 *1024;
    const __bf16* Bb = zT  + (size_t)bb*4096*1536;
    const int lrow = lane >> 2, lseg = lane & 3;
    const int m15 = lane & 15, quad = lane >> 4;
    const int wq = (w >> 1)*64, wf = (w & 1)*64;
    const int rb0 = w*32;                        // rows this wave stages (2 x 16)

    f32x4 acc[4][4] = {};

    auto stage = [&](int buf, int it) {
        const int j0 = it * 32;
        #pragma unroll
        for (int i = 0; i < 2; ++i) {
            const int rb = rb0 + i*16;           // LDS dest = wave-uniform base + lane*16
            gload_lds16(Ab + (size_t)(q0  + rb + lrow)*1024 + j0       + lseg*8, &As[buf][rb*32]);
            gload_lds16(Bb + (size_t)(f20 + rb + lrow)*1536 + 512 + j0 + lseg*8, &Bs[buf][rb*32]);
        }
    };
    auto compute = [&](int buf) {
        bf16x8 av[4], bv[4];
        const int co = quad*8;
        #pragma unroll
        for (int i = 0; i < 4; ++i) av[i] = *(const bf16x8*)(&As[buf][(wq + i*16 + m15)*32 + co]);
        #pragma unroll
        for (int j = 0; j < 4; ++j) bv[j] = *(const bf16x8*)(&Bs[buf][(wf + j*16 + m15)*32 + co]);
        #pragma unroll
        for (int i = 0; i < 4; ++i)
            #pragma unroll
            for (int j = 0; j < 4; ++j)
                acc[i][j] = __builtin_amdgcn_mfma_f32_16x16x32_bf16(av[i], bv[j], acc[i][j], 0, 0, 0);
    };

    stage(0, 0);
    __syncthreads();
    int cur = 0;
    for (int it = 0; it < 31; ++it) {            // K' = 1024 -> 32 steps of 32
        stage(cur ^ 1, it + 1);
        compute(cur);
        __syncthreads();
        cur ^= 1;
    }
    compute(cur);

    // k=0 diagonal epilogue: acc[i][j][rr] += ds[b,q,q] * z0[f2][q],  q = qb+rr
    const float* dsdb = dsd + bb*512;
    #pragma unroll
    for (int i = 0; i < 4; ++i) {
        const int qb = q0 + wq + i*16 + quad*4;
        const float4 dv = *(const float4*)(dsdb + qb);
        #pragma unroll
        for (int j = 0; j < 4; ++j) {
            const int f2 = f20 + wf + j*16 + m15;
            const ushort4 zv = *(const ushort4*)((const unsigned short*)Bb + (size_t)f2*1536 + qb);
            acc[i][j][0] += dv.x * bf2f(zv.x);
            acc[i][j][1] += dv.y * bf2f(zv.y);
            acc[i][j][2] += dv.z * bf2f(zv.z);
            acc[i][j][3] += dv.w * bf2f(zv.w);
        }
    }

    const int b = b0 + bb;
    #pragma unroll
    for (int j = 0; j < 4; ++j) {
        const int f2 = f20 + wf + j*16 + m15;
        const int o = f2 >> 6, l = f2 & 63;
        const float bi = bias[o];
        #pragma unroll
        for (int i = 0; i < 4; ++i) {
            const int qb = q0 + wq + i*16 + quad*4;
            float* dst = out + (((size_t)b*64 + o)*512 + qb)*64 + l;
            dst[  0] = acc[i][j][0] + bi;        // q-stride in out is 64 floats
            dst[ 64] = acc[i][j][1] + bi;
            dst[128] = acc[i][j][2] + bi;
            dst[192] = acc[i][j][3] + bi;
        }
    }
}

// ---------- host ----------
extern "C" void kernel_launch(void* const* d_in, const int* in_sizes, int n_in,
                              void* d_out, int out_size, void* d_ws, size_t ws_size,
                              hipStream_t stream) {
    (void)in_sizes; (void)n_in; (void)out_size;
    const float* x    = (const float*)d_in[0];
    const float* adj  = (const float*)d_in[1];
    const float* ds   = (const float*)d_in[2];
    const float* W    = (const float*)d_in[3];
    const float* bias = (const float*)d_in[4];
    float* out = (float*)d_out;
    char*  ws  = (char*)d_ws;

    float*  T2f  = (float*)ws;                          // 512*512*4 = 1 MiB
    __bf16* W2bf = (__bf16*)(ws + (1u << 20));          // 24576 B
    float*  dsd  = (float*)(ws + (1u << 20) + 32768);   // 32*512*4 = 64 KiB
    char*   chunk0 = ws + (1u << 20) + 32768 + 65536;

    const size_t abytes = (size_t)512 *1024*2;          // per-b Abf  (1 MiB, k=1,2 only)
    const size_t zbytes = (size_t)4096*1536*2;          // per-b zT   (12 MiB)
    const size_t perb   = abytes + zbytes;
    const size_t head   = (1u << 20) + 32768 + 65536;

    int bpc = 1;                                        // batches per chunk, sized to ws
    if (ws_size > head) {
        size_t a = (ws_size - head) / perb;
        bpc = (a < 1) ? 1 : (a > 32 ? 32 : (int)a);
    }

    k_t2<<<dim3(512), dim3(256), 0, stream>>>(adj, T2f);
    k_w2<<<dim3(48),  dim3(256), 0, stream>>>(W, W2bf);

    __bf16* Abf = (__bf16*)chunk0;
    __bf16* zTp = (__bf16*)(chunk0 + (size_t)bpc*abytes);
    for (int b0 = 0; b0 < 32; b0 += bpc) {
        const int bc = (32 - b0 < bpc) ? (32 - b0) : bpc;
        k_abuild<<<dim3(bc*512), dim3(256), 0, stream>>>(ds, adj, T2f, Abf, dsd, b0);
        k_zprep <<<dim3(bc*256), dim3(256), 0, stream>>>(x, W2bf, zTp, b0);
        k_gemm  <<<dim3(bc*128), dim3(256), 0, stream>>>(Abf, zTp, dsd, bias, out, b0);
    }
}